// Round 4
// baseline (408.746 us; speedup 1.0000x reference)
//
#include <hip/hip_runtime.h>

#define B_WIN 1024
#define NTOK 64
#define CDIM 256
#define NH 8
#define HD 32

typedef __attribute__((ext_vector_type(8))) short short8;
typedef __attribute__((ext_vector_type(4))) float f32x4;

__device__ __forceinline__ unsigned short f2bf(float f) {
    unsigned int u = __float_as_uint(f);
    u += 0x7fff + ((u >> 16) & 1);   // round-to-nearest-even
    return (unsigned short)(u >> 16);
}

// ---------------- prep: transpose + convert weights to bf16 ----------------
__global__ void prep_weights(const float* __restrict__ w_qkv,
                             const float* __restrict__ w_proj,
                             unsigned short* __restrict__ wqkvT,
                             unsigned short* __restrict__ wprojT) {
    int tid = blockIdx.x * blockDim.x + threadIdx.x;
    int stride = gridDim.x * blockDim.x;
    for (int i = tid; i < 768 * 256; i += stride) {
        int c = i >> 8, k = i & 255;
        wqkvT[i] = f2bf(w_qkv[k * 768 + c]);
    }
    for (int i = tid; i < 256 * 256; i += stride) {
        int c = i >> 8, k = i & 255;
        wprojT[i] = f2bf(w_proj[k * 256 + c]);
    }
}

// ---------------- kernel 1: fused QKV projection GEMM ----------------------
// per-window block. Stage x (64x256 fp32) ONCE into LDS as bf16 (swizzled),
// then 4 waves x 3 chunks of 64 cols: A from LDS ds_read_b128, B from L2.
__global__ __launch_bounds__(256, 4) void qkv_gemm(
    const float* __restrict__ x, const float* __restrict__ b_qkv,
    const unsigned short* __restrict__ wqkvT,
    unsigned short* __restrict__ Qws, unsigned short* __restrict__ Kws,
    unsigned short* __restrict__ VTws, int wbase) {
    __shared__ unsigned short xbf[64 * 256];   // 32 KB, XOR-swizzled 16B slots
    const int bw = blockIdx.x;
    const int b = wbase + bw;
    const int tid = threadIdx.x;
    const int wv = tid >> 6;
    const int lane = tid & 63;
    const int lr = lane & 15;
    const int g = lane >> 4;
    const float scale = 0.17677669529663687f;  // hd^-0.5

    // ---- stage x -> LDS bf16 (coalesced f32x4 loads, one pass) ----
    {
        const float* xwin = x + (size_t)b * NTOK * CDIM;
        #pragma unroll
        for (int i = 0; i < 16; ++i) {
            int flat = i * 1024 + tid * 4;          // element index
            f32x4 v = *(const f32x4*)(xwin + flat);
            int row = flat >> 8;
            int col = flat & 255;
            ushort4 pk;
            pk.x = f2bf(v[0]); pk.y = f2bf(v[1]);
            pk.z = f2bf(v[2]); pk.w = f2bf(v[3]);
            int byte = (row * 512 + col * 2) ^ ((row & 7) << 4);
            *(ushort4*)((char*)xbf + byte) = pk;
        }
    }
    __syncthreads();

    for (int ch = 0; ch < 3; ++ch) {
        const int c0 = wv * 192 + ch * 64;
        f32x4 acc[4][4];
        #pragma unroll
        for (int i = 0; i < 4; ++i)
            #pragma unroll
            for (int j = 0; j < 4; ++j)
                acc[i][j] = (f32x4){0.f, 0.f, 0.f, 0.f};

        for (int kt = 0; kt < 8; ++kt) {
            short8 af[4];
            #pragma unroll
            for (int mt = 0; mt < 4; ++mt) {
                int row = mt * 16 + lr;
                int byte = (row * 512 + kt * 64 + g * 16) ^ ((row & 7) << 4);
                af[mt] = *(const short8*)((char*)xbf + byte);
            }
            #pragma unroll
            for (int ct = 0; ct < 4; ++ct) {
                short8 bfr = *(const short8*)(wqkvT + (size_t)(c0 + ct * 16 + lr) * CDIM + kt * 32 + g * 8);
                #pragma unroll
                for (int mt = 0; mt < 4; ++mt)
                    acc[mt][ct] = __builtin_amdgcn_mfma_f32_16x16x32_bf16(
                        af[mt], bfr, acc[mt][ct], 0, 0, 0);
            }
        }
        // epilogue: bias (+scale for Q), scatter to ws
        #pragma unroll
        for (int ct = 0; ct < 4; ++ct) {
            int c = c0 + ct * 16 + lr;
            int m = c >> 8;           // 0=Q 1=K 2=V (uniform per 16-lane group)
            int rem = c & 255;
            int h = rem >> 5, d = rem & 31;
            float bias = b_qkv[c];
            #pragma unroll
            for (int mt = 0; mt < 4; ++mt) {
                int n0 = mt * 16 + g * 4;
                if (m == 2) {
                    unsigned short* dst =
                        VTws + ((size_t)(bw * NH + h) * HD + d) * NTOK + n0;
                    ushort4 pk;
                    pk.x = f2bf(acc[mt][ct][0] + bias);
                    pk.y = f2bf(acc[mt][ct][1] + bias);
                    pk.z = f2bf(acc[mt][ct][2] + bias);
                    pk.w = f2bf(acc[mt][ct][3] + bias);
                    *(ushort4*)dst = pk;
                } else {
                    unsigned short* base =
                        (m == 0 ? Qws : Kws) + (size_t)(bw * NH + h) * NTOK * HD + d;
                    float mul = (m == 0) ? scale : 1.0f;
                    #pragma unroll
                    for (int r = 0; r < 4; ++r)
                        base[(n0 + r) * HD] = f2bf((acc[mt][ct][r] + bias) * mul);
                }
            }
        }
    }
}

// ---------------- kernel 2: attention + fused output projection ------------
// per-window block, 4 waves; each wave does heads {wv, wv+4} (fully unrolled,
// O kept in registers). LDS is a 32KB union: per-wave P scratch during the
// head loop, then the 64x256 attn-out tile for the out-proj GEMM.
__global__ __launch_bounds__(256, 3) void attn_proj(
    const unsigned short* __restrict__ Qws, const unsigned short* __restrict__ Kws,
    const unsigned short* __restrict__ VTws, const float* __restrict__ mask,
    const unsigned short* __restrict__ wprojT, const float* __restrict__ b_proj,
    float* __restrict__ out, int wbase) {
    __shared__ unsigned short shb[64 * 256];   // 32KB union: P scratch / attn-out

    const int bw = blockIdx.x;
    const int b = wbase + bw;
    const int tid = threadIdx.x;
    const int wv = tid >> 6;
    const int lane = tid & 63;
    const int lr = lane & 15;
    const int g = lane >> 4;
    const float* mwin = mask + (size_t)(b & 63) * NTOK * NTOK;

    f32x4 o[2][4][2];
    #pragma unroll
    for (int i = 0; i < 2; ++i)
        #pragma unroll
        for (int mt = 0; mt < 4; ++mt)
            #pragma unroll
            for (int dt = 0; dt < 2; ++dt)
                o[i][mt][dt] = (f32x4){0.f, 0.f, 0.f, 0.f};

    unsigned short* pl = shb + wv * 4096;      // per-wave 8KB P scratch

    #pragma unroll
    for (int hi2 = 0; hi2 < 2; ++hi2) {
        const int h = wv + hi2 * 4;
        const unsigned short* Qh = Qws + (size_t)(bw * NH + h) * NTOK * HD;
        const unsigned short* Kh = Kws + (size_t)(bw * NH + h) * NTOK * HD;
        const unsigned short* Vh = VTws + (size_t)(bw * NH + h) * HD * NTOK;

        // ---- S = Q K^T ----
        short8 qf[4], kf[4];
        #pragma unroll
        for (int t = 0; t < 4; ++t) {
            qf[t] = *(const short8*)(Qh + (t * 16 + lr) * HD + g * 8);
            kf[t] = *(const short8*)(Kh + (t * 16 + lr) * HD + g * 8);
        }
        f32x4 s[4][4];
        #pragma unroll
        for (int mt = 0; mt < 4; ++mt)
            #pragma unroll
            for (int nt = 0; nt < 4; ++nt)
                s[mt][nt] = __builtin_amdgcn_mfma_f32_16x16x32_bf16(
                    qf[mt], kf[nt], (f32x4){0.f, 0.f, 0.f, 0.f}, 0, 0, 0);

        // ---- mask add + row softmax + P -> LDS ----
        #pragma unroll
        for (int mt = 0; mt < 4; ++mt) {
            #pragma unroll
            for (int r = 0; r < 4; ++r) {
                int n = mt * 16 + g * 4 + r;
                const float* mrow = mwin + n * 64 + lr;
                float v0 = s[mt][0][r] + mrow[0];
                float v1 = s[mt][1][r] + mrow[16];
                float v2 = s[mt][2][r] + mrow[32];
                float v3 = s[mt][3][r] + mrow[48];
                float mx = fmaxf(fmaxf(v0, v1), fmaxf(v2, v3));
                #pragma unroll
                for (int sh = 1; sh < 16; sh <<= 1) mx = fmaxf(mx, __shfl_xor(mx, sh));
                v0 = __expf(v0 - mx); v1 = __expf(v1 - mx);
                v2 = __expf(v2 - mx); v3 = __expf(v3 - mx);
                float sum = v0 + v1 + v2 + v3;
                #pragma unroll
                for (int sh = 1; sh < 16; sh <<= 1) sum += __shfl_xor(sum, sh);
                float inv = 1.0f / sum;
                int rb = n * 64;
                int sw = (n & 7) << 3;
                pl[(rb + lr)      ^ sw] = f2bf(v0 * inv);
                pl[(rb + lr + 16) ^ sw] = f2bf(v1 * inv);
                pl[(rb + lr + 32) ^ sw] = f2bf(v2 * inv);
                pl[(rb + lr + 48) ^ sw] = f2bf(v3 * inv);
            }
        }

        // ---- O = P V (accumulate in regs, kept until after head loop) ----
        #pragma unroll
        for (int kt2 = 0; kt2 < 2; ++kt2) {
            short8 pa[4], vf[2];
            #pragma unroll
            for (int mt = 0; mt < 4; ++mt) {
                int row = mt * 16 + lr;
                int idx = (row * 64 + kt2 * 32 + g * 8) ^ ((row & 7) << 3);
                pa[mt] = *(const short8*)(pl + idx);
            }
            #pragma unroll
            for (int dt = 0; dt < 2; ++dt)
                vf[dt] = *(const short8*)(Vh + (dt * 16 + lr) * NTOK + kt2 * 32 + g * 8);
            #pragma unroll
            for (int mt = 0; mt < 4; ++mt)
                #pragma unroll
                for (int dt = 0; dt < 2; ++dt)
                    o[hi2][mt][dt] = __builtin_amdgcn_mfma_f32_16x16x32_bf16(
                        pa[mt], vf[dt], o[hi2][mt][dt], 0, 0, 0);
        }
    }
    __syncthreads();   // all P usage complete; shb becomes attn-out tile

    // ---- attn-out -> LDS (swizzled), layout [n][h*32+d] ----
    #pragma unroll
    for (int hi2 = 0; hi2 < 2; ++hi2) {
        int h = wv + hi2 * 4;
        #pragma unroll
        for (int mt = 0; mt < 4; ++mt)
            #pragma unroll
            for (int dt = 0; dt < 2; ++dt) {
                int c = h * 32 + dt * 16 + lr;
                #pragma unroll
                for (int r = 0; r < 4; ++r) {
                    int n = mt * 16 + g * 4 + r;
                    shb[(n * 256 + c) ^ ((n & 7) << 3)] = f2bf(o[hi2][mt][dt][r]);
                }
            }
    }
    __syncthreads();

    // ---- out-proj: (64x256) @ (256x256) + bias ----
    f32x4 acc2[4][4];
    #pragma unroll
    for (int i = 0; i < 4; ++i)
        #pragma unroll
        for (int j = 0; j < 4; ++j)
            acc2[i][j] = (f32x4){0.f, 0.f, 0.f, 0.f};
    const int c0 = wv * 64;
    for (int kt = 0; kt < 8; ++kt) {
        short8 af2[4];
        #pragma unroll
        for (int mt = 0; mt < 4; ++mt) {
            int row = mt * 16 + lr;
            int idx = (row * 256 + kt * 32 + g * 8) ^ ((row & 7) << 3);
            af2[mt] = *(const short8*)(shb + idx);
        }
        #pragma unroll
        for (int ct = 0; ct < 4; ++ct) {
            short8 bf2 = *(const short8*)(wprojT + (size_t)(c0 + ct * 16 + lr) * 256 + kt * 32 + g * 8);
            #pragma unroll
            for (int mt = 0; mt < 4; ++mt)
                acc2[mt][ct] = __builtin_amdgcn_mfma_f32_16x16x32_bf16(
                    af2[mt], bf2, acc2[mt][ct], 0, 0, 0);
        }
    }
    float* ob = out + (size_t)b * NTOK * CDIM;
    #pragma unroll
    for (int ct = 0; ct < 4; ++ct) {
        int c = c0 + ct * 16 + lr;
        float bias = b_proj[c];
        #pragma unroll
        for (int mt = 0; mt < 4; ++mt)
            #pragma unroll
            for (int r = 0; r < 4; ++r) {
                int n = mt * 16 + g * 4 + r;
                ob[n * 256 + c] = acc2[mt][ct][r] + bias;
            }
    }
}

extern "C" void kernel_launch(void* const* d_in, const int* in_sizes, int n_in,
                              void* d_out, int out_size, void* d_ws, size_t ws_size,
                              hipStream_t stream) {
    const float* x      = (const float*)d_in[0];
    const float* mask   = (const float*)d_in[1];
    const float* w_qkv  = (const float*)d_in[2];
    const float* b_qkv  = (const float*)d_in[3];
    const float* w_proj = (const float*)d_in[4];
    const float* b_proj = (const float*)d_in[5];
    float* out = (float*)d_out;

    // ws layout: [wqkvT 768*256][wprojT 256*256][Q | K | VT for W windows]
    const size_t wT_elems = 768 * 256 + 256 * 256;
    const size_t per_win  = (size_t)NH * NTOK * HD * 3;

    size_t avail = ws_size / 2;   // bf16 elems
    int W = 1024;
    while (W > 1 && wT_elems + (size_t)W * per_win > avail) W >>= 1;

    unsigned short* wqkvT  = (unsigned short*)d_ws;
    unsigned short* wprojT = wqkvT + 768 * 256;
    unsigned short* Qws    = wprojT + 256 * 256;
    unsigned short* Kws    = Qws + (size_t)W * NH * NTOK * HD;
    unsigned short* VTws   = Kws + (size_t)W * NH * NTOK * HD;

    prep_weights<<<256, 256, 0, stream>>>(w_qkv, w_proj, wqkvT, wprojT);
    for (int wbase = 0; wbase < B_WIN; wbase += W) {
        qkv_gemm<<<W, 256, 0, stream>>>(x, b_qkv, wqkvT, Qws, Kws, VTws, wbase);
        attn_proj<<<W, 256, 0, stream>>>(Qws, Kws, VTws, mask, wprojT, b_proj,
                                         out, wbase);
    }
}

// Round 5
// 361.421 us; speedup vs baseline: 1.1309x; 1.1309x over previous
//
#include <hip/hip_runtime.h>

#define B_WIN 1024
#define NTOK 64
#define CDIM 256
#define NH 8
#define HD 32

typedef __attribute__((ext_vector_type(8))) short short8;
typedef __attribute__((ext_vector_type(4))) float f32x4;

__device__ __forceinline__ unsigned short f2bf(float f) {
    unsigned int u = __float_as_uint(f);
    u += 0x7fff + ((u >> 16) & 1);   // round-to-nearest-even
    return (unsigned short)(u >> 16);
}

// ---------------- prep: transpose + convert weights to bf16 ----------------
__global__ void prep_weights(const float* __restrict__ w_qkv,
                             const float* __restrict__ w_proj,
                             unsigned short* __restrict__ wqkvT,
                             unsigned short* __restrict__ wprojT) {
    int tid = blockIdx.x * blockDim.x + threadIdx.x;
    int stride = gridDim.x * blockDim.x;
    for (int i = tid; i < 768 * 256; i += stride) {
        int c = i >> 8, k = i & 255;
        wqkvT[i] = f2bf(w_qkv[k * 768 + c]);
    }
    for (int i = tid; i < 256 * 256; i += stride) {
        int c = i >> 8, k = i & 255;
        wprojT[i] = f2bf(w_proj[k * 256 + c]);
    }
}

// ---------------- kernel 1: fused QKV projection GEMM ----------------------
// per-window block. x staged once in LDS (bf16, swizzled). Wave wv computes,
// per ch = matrix {Q,K,V}, the 64x64 tile for heads {wv, wv+4}. Epilogue goes
// through a wave-private 4KB LDS staging tile so EVERY global store is a
// full-cacheline 16B-per-lane coalesced write (fixes round-4's L2 RMW thrash:
// FETCH/WRITE 258/260 MB -> expect ~75/~105).
__global__ __launch_bounds__(256, 3) void qkv_gemm(
    const float* __restrict__ x, const float* __restrict__ b_qkv,
    const unsigned short* __restrict__ wqkvT,
    unsigned short* __restrict__ Qws, unsigned short* __restrict__ Kws,
    unsigned short* __restrict__ VTws, int wbase) {
    __shared__ unsigned short xbf[64 * 256];     // 32 KB
    __shared__ unsigned short stg[4][64 * 32];   // 16 KB, 4KB per wave
    const int bw = blockIdx.x;
    const int b = wbase + bw;
    const int tid = threadIdx.x;
    const int wv = tid >> 6;
    const int lane = tid & 63;
    const int lr = lane & 15;
    const int g = lane >> 4;
    const float scale = 0.17677669529663687f;  // hd^-0.5

    // ---- stage x -> LDS bf16 ----
    {
        const float* xwin = x + (size_t)b * NTOK * CDIM;
        #pragma unroll
        for (int i = 0; i < 16; ++i) {
            int flat = i * 1024 + tid * 4;
            f32x4 v = *(const f32x4*)(xwin + flat);
            int row = flat >> 8;
            int col = flat & 255;
            ushort4 pk;
            pk.x = f2bf(v[0]); pk.y = f2bf(v[1]);
            pk.z = f2bf(v[2]); pk.w = f2bf(v[3]);
            int byte = (row * 512 + col * 2) ^ ((row & 7) << 4);
            *(ushort4*)((char*)xbf + byte) = pk;
        }
    }
    __syncthreads();

    unsigned short* sp = stg[wv];

    for (int ch = 0; ch < 3; ++ch) {          // 0=Q 1=K 2=V
        f32x4 acc[4][4];
        #pragma unroll
        for (int i = 0; i < 4; ++i)
            #pragma unroll
            for (int j = 0; j < 4; ++j)
                acc[i][j] = (f32x4){0.f, 0.f, 0.f, 0.f};

        for (int kt = 0; kt < 8; ++kt) {
            short8 af[4];
            #pragma unroll
            for (int mt = 0; mt < 4; ++mt) {
                int row = mt * 16 + lr;
                int byte = (row * 512 + kt * 64 + g * 16) ^ ((row & 7) << 4);
                af[mt] = *(const short8*)((char*)xbf + byte);
            }
            #pragma unroll
            for (int ct = 0; ct < 4; ++ct) {
                // column tile: head h = wv + (ct>>1)*4, d-half = ct&1
                int c = ch * 256 + (wv + (ct >> 1) * 4) * 32 + (ct & 1) * 16 + lr;
                short8 bfr = *(const short8*)(wqkvT + (size_t)c * CDIM + kt * 32 + g * 8);
                #pragma unroll
                for (int mt = 0; mt < 4; ++mt)
                    acc[mt][ct] = __builtin_amdgcn_mfma_f32_16x16x32_bf16(
                        af[mt], bfr, acc[mt][ct], 0, 0, 0);
            }
        }

        const float mul = (ch == 0) ? scale : 1.0f;
        #pragma unroll
        for (int hs = 0; hs < 2; ++hs) {
            const int h = wv + hs * 4;
            // ---- stage this head's 64x32 tile into wave-private LDS ----
            if (ch < 2) {
                // layout [n][d] (32 shorts per row)
                #pragma unroll
                for (int ct2 = 0; ct2 < 2; ++ct2) {
                    int ctg = hs * 2 + ct2;
                    int c = ch * 256 + h * 32 + ct2 * 16 + lr;
                    float bias = b_qkv[c];
                    #pragma unroll
                    for (int mt = 0; mt < 4; ++mt)
                        #pragma unroll
                        for (int r = 0; r < 4; ++r) {
                            int n = mt * 16 + g * 4 + r;
                            sp[n * 32 + ct2 * 16 + lr] =
                                f2bf((acc[mt][ctg][r] + bias) * mul);
                        }
                }
            } else {
                // layout [d][n] (V^T), XOR-swizzled to break d-column banks
                #pragma unroll
                for (int ct2 = 0; ct2 < 2; ++ct2) {
                    int ctg = hs * 2 + ct2;
                    int d = ct2 * 16 + lr;
                    int c = 512 + h * 32 + d;
                    float bias = b_qkv[c];
                    #pragma unroll
                    for (int mt = 0; mt < 4; ++mt)
                        #pragma unroll
                        for (int r = 0; r < 4; ++r) {
                            int n = mt * 16 + g * 4 + r;
                            sp[(d * 64 + n) ^ ((d & 7) << 3)] =
                                f2bf(acc[mt][ctg][r] + bias);
                        }
                }
            }
            __syncthreads();   // staging visible (and uniform across waves)

            // ---- full-line coalesced global write ----
            if (ch < 2) {
                unsigned short* dst =
                    (ch == 0 ? Qws : Kws) + (size_t)(bw * NH + h) * NTOK * HD;
                #pragma unroll
                for (int i2 = 0; i2 < 4; ++i2) {
                    int row = i2 * 16 + (lane >> 2);
                    int colc = (lane & 3) * 8;
                    short8 vv = *(const short8*)(sp + row * 32 + colc);
                    *(short8*)(dst + row * 32 + colc) = vv;   // 4 lanes = 64B line
                }
            } else {
                unsigned short* dst = VTws + (size_t)(bw * NH + h) * HD * NTOK;
                #pragma unroll
                for (int i2 = 0; i2 < 4; ++i2) {
                    int d = i2 * 8 + (lane >> 3);
                    int nc = (lane & 7) * 8;
                    short8 vv = *(const short8*)(sp + ((d * 64 + nc) ^ ((d & 7) << 3)));
                    *(short8*)(dst + d * 64 + nc) = vv;       // 8 lanes = 128B row
                }
            }
            __syncthreads();   // reads done before next hs reuses stg
        }
    }
}

// ---------------- kernel 2: attention + fused output projection ------------
// per-window block, 4 waves; wave handles heads {wv, wv+4}. Per-mt fused
// softmax (low s-liveness); O packed to bf16 right after each head's PV.
// LDS 32KB union (per-wave P scratch -> attn-out tile); 4 blocks/CU so all
// 1024 blocks are resident in a single round.
__global__ __launch_bounds__(256, 4) void attn_proj(
    const unsigned short* __restrict__ Qws, const unsigned short* __restrict__ Kws,
    const unsigned short* __restrict__ VTws, const float* __restrict__ mask,
    const unsigned short* __restrict__ wprojT, const float* __restrict__ b_proj,
    float* __restrict__ out, int wbase) {
    __shared__ unsigned short shb[64 * 256];   // 32KB union: P scratch / attn-out

    const int bw = blockIdx.x;
    const int b = wbase + bw;
    const int tid = threadIdx.x;
    const int wv = tid >> 6;
    const int lane = tid & 63;
    const int lr = lane & 15;
    const int g = lane >> 4;
    const float* mwin = mask + (size_t)(b & 63) * NTOK * NTOK;

    short8 ob16[2][4];                         // packed O, elem = dt*4+r
    unsigned short* pl = shb + wv * 4096;      // per-wave 8KB P scratch

    #pragma unroll
    for (int hi2 = 0; hi2 < 2; ++hi2) {
        const int h = wv + hi2 * 4;
        const unsigned short* Qh = Qws + (size_t)(bw * NH + h) * NTOK * HD;
        const unsigned short* Kh = Kws + (size_t)(bw * NH + h) * NTOK * HD;
        const unsigned short* Vh = VTws + (size_t)(bw * NH + h) * HD * NTOK;

        short8 qf[4], kf[4];
        #pragma unroll
        for (int t = 0; t < 4; ++t) {
            qf[t] = *(const short8*)(Qh + (t * 16 + lr) * HD + g * 8);
            kf[t] = *(const short8*)(Kh + (t * 16 + lr) * HD + g * 8);
        }

        // ---- per-mt: QK^T row of tiles -> mask+softmax -> P to LDS ----
        #pragma unroll
        for (int mt = 0; mt < 4; ++mt) {
            f32x4 srow[4];
            #pragma unroll
            for (int nt = 0; nt < 4; ++nt)
                srow[nt] = __builtin_amdgcn_mfma_f32_16x16x32_bf16(
                    qf[mt], kf[nt], (f32x4){0.f, 0.f, 0.f, 0.f}, 0, 0, 0);
            #pragma unroll
            for (int r = 0; r < 4; ++r) {
                int n = mt * 16 + g * 4 + r;
                const float* mrow = mwin + n * 64 + lr;
                float v0 = srow[0][r] + mrow[0];
                float v1 = srow[1][r] + mrow[16];
                float v2 = srow[2][r] + mrow[32];
                float v3 = srow[3][r] + mrow[48];
                float mx = fmaxf(fmaxf(v0, v1), fmaxf(v2, v3));
                #pragma unroll
                for (int sh = 1; sh < 16; sh <<= 1) mx = fmaxf(mx, __shfl_xor(mx, sh));
                v0 = __expf(v0 - mx); v1 = __expf(v1 - mx);
                v2 = __expf(v2 - mx); v3 = __expf(v3 - mx);
                float sum = v0 + v1 + v2 + v3;
                #pragma unroll
                for (int sh = 1; sh < 16; sh <<= 1) sum += __shfl_xor(sum, sh);
                float inv = 1.0f / sum;
                int rb = n * 64;
                int sw = (n & 7) << 3;
                pl[(rb + lr)      ^ sw] = f2bf(v0 * inv);
                pl[(rb + lr + 16) ^ sw] = f2bf(v1 * inv);
                pl[(rb + lr + 32) ^ sw] = f2bf(v2 * inv);
                pl[(rb + lr + 48) ^ sw] = f2bf(v3 * inv);
            }
        }

        // ---- O = P V, then pack to bf16 immediately ----
        f32x4 o[4][2];
        #pragma unroll
        for (int mt = 0; mt < 4; ++mt)
            #pragma unroll
            for (int dt = 0; dt < 2; ++dt)
                o[mt][dt] = (f32x4){0.f, 0.f, 0.f, 0.f};
        #pragma unroll
        for (int kt2 = 0; kt2 < 2; ++kt2) {
            short8 pa[4], vf[2];
            #pragma unroll
            for (int mt = 0; mt < 4; ++mt) {
                int row = mt * 16 + lr;
                int idx = (row * 64 + kt2 * 32 + g * 8) ^ ((row & 7) << 3);
                pa[mt] = *(const short8*)(pl + idx);
            }
            #pragma unroll
            for (int dt = 0; dt < 2; ++dt)
                vf[dt] = *(const short8*)(Vh + (dt * 16 + lr) * NTOK + kt2 * 32 + g * 8);
            #pragma unroll
            for (int mt = 0; mt < 4; ++mt)
                #pragma unroll
                for (int dt = 0; dt < 2; ++dt)
                    o[mt][dt] = __builtin_amdgcn_mfma_f32_16x16x32_bf16(
                        pa[mt], vf[dt], o[mt][dt], 0, 0, 0);
        }
        #pragma unroll
        for (int mt = 0; mt < 4; ++mt) {
            short8 p;
            #pragma unroll
            for (int dt = 0; dt < 2; ++dt)
                #pragma unroll
                for (int r = 0; r < 4; ++r)
                    p[dt * 4 + r] = (short)f2bf(o[mt][dt][r]);
            ob16[hi2][mt] = p;
        }
    }
    __syncthreads();   // all P usage complete; shb becomes attn-out tile

    // ---- attn-out -> LDS (swizzled), layout [n][h*32+d] ----
    #pragma unroll
    for (int hi2 = 0; hi2 < 2; ++hi2) {
        int h = wv + hi2 * 4;
        #pragma unroll
        for (int mt = 0; mt < 4; ++mt)
            #pragma unroll
            for (int dt = 0; dt < 2; ++dt) {
                int c = h * 32 + dt * 16 + lr;
                #pragma unroll
                for (int r = 0; r < 4; ++r) {
                    int n = mt * 16 + g * 4 + r;
                    shb[(n * 256 + c) ^ ((n & 7) << 3)] =
                        (unsigned short)ob16[hi2][mt][dt * 4 + r];
                }
            }
    }
    __syncthreads();

    // ---- out-proj: (64x256) @ (256x256) + bias ----
    f32x4 acc2[4][4];
    #pragma unroll
    for (int i = 0; i < 4; ++i)
        #pragma unroll
        for (int j = 0; j < 4; ++j)
            acc2[i][j] = (f32x4){0.f, 0.f, 0.f, 0.f};
    const int c0 = wv * 64;
    for (int kt = 0; kt < 8; ++kt) {
        short8 af2[4];
        #pragma unroll
        for (int mt = 0; mt < 4; ++mt) {
            int row = mt * 16 + lr;
            int idx = (row * 256 + kt * 32 + g * 8) ^ ((row & 7) << 3);
            af2[mt] = *(const short8*)(shb + idx);
        }
        #pragma unroll
        for (int ct = 0; ct < 4; ++ct) {
            short8 bf2 = *(const short8*)(wprojT + (size_t)(c0 + ct * 16 + lr) * 256 + kt * 32 + g * 8);
            #pragma unroll
            for (int mt = 0; mt < 4; ++mt)
                acc2[mt][ct] = __builtin_amdgcn_mfma_f32_16x16x32_bf16(
                    af2[mt], bf2, acc2[mt][ct], 0, 0, 0);
        }
    }
    float* ob = out + (size_t)b * NTOK * CDIM;
    #pragma unroll
    for (int ct = 0; ct < 4; ++ct) {
        int c = c0 + ct * 16 + lr;
        float bias = b_proj[c];
        #pragma unroll
        for (int mt = 0; mt < 4; ++mt)
            #pragma unroll
            for (int r = 0; r < 4; ++r) {
                int n = mt * 16 + g * 4 + r;
                ob[n * 256 + c] = acc2[mt][ct][r] + bias;
            }
    }
}

extern "C" void kernel_launch(void* const* d_in, const int* in_sizes, int n_in,
                              void* d_out, int out_size, void* d_ws, size_t ws_size,
                              hipStream_t stream) {
    const float* x      = (const float*)d_in[0];
    const float* mask   = (const float*)d_in[1];
    const float* w_qkv  = (const float*)d_in[2];
    const float* b_qkv  = (const float*)d_in[3];
    const float* w_proj = (const float*)d_in[4];
    const float* b_proj = (const float*)d_in[5];
    float* out = (float*)d_out;

    const size_t wT_elems = 768 * 256 + 256 * 256;
    const size_t per_win  = (size_t)NH * NTOK * HD * 3;

    size_t avail = ws_size / 2;   // bf16 elems
    int W = 1024;
    while (W > 1 && wT_elems + (size_t)W * per_win > avail) W >>= 1;

    unsigned short* wqkvT  = (unsigned short*)d_ws;
    unsigned short* wprojT = wqkvT + 768 * 256;
    unsigned short* Qws    = wprojT + 256 * 256;
    unsigned short* Kws    = Qws + (size_t)W * NH * NTOK * HD;
    unsigned short* VTws   = Kws + (size_t)W * NH * NTOK * HD;

    prep_weights<<<256, 256, 0, stream>>>(w_qkv, w_proj, wqkvT, wprojT);
    for (int wbase = 0; wbase < B_WIN; wbase += W) {
        qkv_gemm<<<W, 256, 0, stream>>>(x, b_qkv, wqkvT, Qws, Kws, VTws, wbase);
        attn_proj<<<W, 256, 0, stream>>>(Qws, Kws, VTws, mask, wprojT, b_proj,
                                         out, wbase);
    }
}

// Round 7
// 265.764 us; speedup vs baseline: 1.5380x; 1.3599x over previous
//
#include <hip/hip_runtime.h>

#define NTOK 64
#define CDIM 256
#define NH 8
#define HD 32

typedef __attribute__((ext_vector_type(8))) short short8;
typedef __attribute__((ext_vector_type(4))) float f32x4;

__device__ __forceinline__ unsigned short f2bf(float f) {
    unsigned int u = __float_as_uint(f);
    u += 0x7fff + ((u >> 16) & 1);   // round-to-nearest-even
    return (unsigned short)(u >> 16);
}

#define LGKM0() asm volatile("s_waitcnt lgkmcnt(0)" ::: "memory")

// ---------------- prep: transpose + convert weights to bf16 ----------------
__global__ void prep_weights(const float* __restrict__ w_qkv,
                             const float* __restrict__ w_proj,
                             unsigned short* __restrict__ wqkvT,
                             unsigned short* __restrict__ wprojT) {
    int tid = blockIdx.x * blockDim.x + threadIdx.x;
    int stride = gridDim.x * blockDim.x;
    for (int i = tid; i < 768 * 256; i += stride) {
        int c = i >> 8, k = i & 255;
        wqkvT[i] = f2bf(w_qkv[k * 768 + c]);
    }
    for (int i = tid; i < 256 * 256; i += stride) {
        int c = i >> 8, k = i & 255;
        wprojT[i] = f2bf(w_proj[k * 256 + c]);
    }
}

// ---------------- fully fused: QKV proj + attention + out proj -------------
// One block per window (256 thr, 4 waves). Wave wv owns heads {wv, wv+4}
// end-to-end; Q/K/V never touch global memory. LDS: xbf 32KB (x staging,
// reused as attn-out tile) + 8KB wave-private scratch (QKV-fragment
// transpose, then P). Only 3 barriers per block; all other LDS reuse is
// intra-wave (in-order DS + explicit lgkmcnt guards).
__global__ __launch_bounds__(256) void swin_fused(
    const float* __restrict__ x, const float* __restrict__ mask,
    const unsigned short* __restrict__ wqkvT, const float* __restrict__ b_qkv,
    const unsigned short* __restrict__ wprojT, const float* __restrict__ b_proj,
    float* __restrict__ out) {
    __shared__ unsigned short xbf[64 * 256];    // 32 KB: x bf16 -> attn-out
    __shared__ unsigned short wbuf[4][4096];    // 8 KB per wave

    const int b = blockIdx.x;
    const int tid = threadIdx.x;
    const int wv = tid >> 6;
    const int lane = tid & 63;
    const int lr = lane & 15;
    const int g = lane >> 4;
    const float scale = 0.17677669529663687f;   // hd^-0.5

    // ---- stage x -> LDS bf16 (swizzled 16B slots) ----
    {
        const float* xwin = x + (size_t)b * NTOK * CDIM;
        #pragma unroll
        for (int i = 0; i < 16; ++i) {
            int flat = i * 1024 + tid * 4;
            f32x4 v = *(const f32x4*)(xwin + flat);
            int row = flat >> 8;
            int col = flat & 255;
            ushort4 pk;
            pk.x = f2bf(v[0]); pk.y = f2bf(v[1]);
            pk.z = f2bf(v[2]); pk.w = f2bf(v[3]);
            int byte = (row * 512 + col * 2) ^ ((row & 7) << 4);
            *(ushort4*)((char*)xbf + byte) = pk;
        }
    }
    __syncthreads();

    const float* mwin = mask + (size_t)(b & 63) * NTOK * NTOK;
    unsigned short* wb = wbuf[wv];
    short8 ob16[2][4];                          // packed O per head

    #pragma unroll
    for (int hi2 = 0; hi2 < 2; ++hi2) {
        const int h = wv + hi2 * 4;
        short8 qkf[2][4];                       // Q and K A/B-fragments
        short8 vf[4];                           // V B-fragments [kt2*2+dt]

        // ---- QKV GEMMs for this head (m: 0=Q 1=K 2=V) ----
        #pragma unroll
        for (int m = 0; m < 3; ++m) {
            f32x4 acc[4][2];
            #pragma unroll
            for (int mt = 0; mt < 4; ++mt)
                #pragma unroll
                for (int ct = 0; ct < 2; ++ct)
                    acc[mt][ct] = (f32x4){0.f, 0.f, 0.f, 0.f};

            for (int kt = 0; kt < 8; ++kt) {
                short8 af[4];
                #pragma unroll
                for (int mt = 0; mt < 4; ++mt) {
                    int row = mt * 16 + lr;
                    int byte = (row * 512 + kt * 64 + g * 16) ^ ((row & 7) << 4);
                    af[mt] = *(const short8*)((char*)xbf + byte);
                }
                #pragma unroll
                for (int ct = 0; ct < 2; ++ct) {
                    int c = m * 256 + h * 32 + ct * 16 + lr;
                    short8 bfr = *(const short8*)(wqkvT + (size_t)c * 256 + kt * 32 + g * 8);
                    #pragma unroll
                    for (int mt = 0; mt < 4; ++mt)
                        acc[mt][ct] = __builtin_amdgcn_mfma_f32_16x16x32_bf16(
                            af[mt], bfr, acc[mt][ct], 0, 0, 0);
                }
            }

            LGKM0();   // prior reads from wb done before we overwrite it
            if (m < 2) {
                // transpose via wave-private LDS: [n][32], XOR ((n>>2)&3)<<3
                const float mul = (m == 0) ? scale : 1.0f;
                #pragma unroll
                for (int ct = 0; ct < 2; ++ct) {
                    float bias = b_qkv[m * 256 + h * 32 + ct * 16 + lr];
                    #pragma unroll
                    for (int mt = 0; mt < 4; ++mt)
                        #pragma unroll
                        for (int r = 0; r < 4; ++r) {
                            int n = mt * 16 + g * 4 + r;
                            wb[(n * 32 + ct * 16 + lr) ^ (((n >> 2) & 3) << 3)] =
                                f2bf((acc[mt][ct][r] + bias) * mul);
                        }
                }
                #pragma unroll
                for (int mt = 0; mt < 4; ++mt) {
                    int n = mt * 16 + lr;
                    qkf[m][mt] = *(const short8*)(
                        wb + ((n * 32 + g * 8) ^ (((n >> 2) & 3) << 3)));
                }
            } else {
                // V^T: [d][64], XOR ((d&7)<<3); ushort4 packed rows
                #pragma unroll
                for (int ct = 0; ct < 2; ++ct) {
                    int d = ct * 16 + lr;
                    float bias = b_qkv[512 + h * 32 + d];
                    #pragma unroll
                    for (int mt = 0; mt < 4; ++mt) {
                        ushort4 pk;
                        pk.x = f2bf(acc[mt][ct][0] + bias);
                        pk.y = f2bf(acc[mt][ct][1] + bias);
                        pk.z = f2bf(acc[mt][ct][2] + bias);
                        pk.w = f2bf(acc[mt][ct][3] + bias);
                        int n0 = mt * 16 + g * 4;
                        *(ushort4*)(wb + ((d * 64 + n0) ^ ((d & 7) << 3))) = pk;
                    }
                }
                #pragma unroll
                for (int kt2 = 0; kt2 < 2; ++kt2)
                    #pragma unroll
                    for (int dt = 0; dt < 2; ++dt) {
                        int d = dt * 16 + lr;
                        vf[kt2 * 2 + dt] = *(const short8*)(
                            wb + ((d * 64 + kt2 * 32 + g * 8) ^ ((d & 7) << 3)));
                    }
            }
        }

        // ---- S = Q K^T, mask+softmax, P -> wb ([n][64], XOR (n&7)<<3) ----
        LGKM0();   // vf reads complete before wb becomes P
        #pragma unroll
        for (int mt = 0; mt < 4; ++mt) {
            f32x4 srow[4];
            #pragma unroll
            for (int nt = 0; nt < 4; ++nt)
                srow[nt] = __builtin_amdgcn_mfma_f32_16x16x32_bf16(
                    qkf[0][mt], qkf[1][nt], (f32x4){0.f, 0.f, 0.f, 0.f}, 0, 0, 0);
            #pragma unroll
            for (int r = 0; r < 4; ++r) {
                int n = mt * 16 + g * 4 + r;
                const float* mrow = mwin + n * 64 + lr;
                float v0 = srow[0][r] + mrow[0];
                float v1 = srow[1][r] + mrow[16];
                float v2 = srow[2][r] + mrow[32];
                float v3 = srow[3][r] + mrow[48];
                float mx = fmaxf(fmaxf(v0, v1), fmaxf(v2, v3));
                #pragma unroll
                for (int sh = 1; sh < 16; sh <<= 1) mx = fmaxf(mx, __shfl_xor(mx, sh));
                v0 = __expf(v0 - mx); v1 = __expf(v1 - mx);
                v2 = __expf(v2 - mx); v3 = __expf(v3 - mx);
                float sum = v0 + v1 + v2 + v3;
                #pragma unroll
                for (int sh = 1; sh < 16; sh <<= 1) sum += __shfl_xor(sum, sh);
                float inv = 1.0f / sum;
                int rb = n * 64;
                int sw = (n & 7) << 3;
                wb[(rb + lr)      ^ sw] = f2bf(v0 * inv);
                wb[(rb + lr + 16) ^ sw] = f2bf(v1 * inv);
                wb[(rb + lr + 32) ^ sw] = f2bf(v2 * inv);
                wb[(rb + lr + 48) ^ sw] = f2bf(v3 * inv);
            }
        }

        // ---- O = P V ----
        f32x4 o[4][2];
        #pragma unroll
        for (int mt = 0; mt < 4; ++mt)
            #pragma unroll
            for (int dt = 0; dt < 2; ++dt)
                o[mt][dt] = (f32x4){0.f, 0.f, 0.f, 0.f};
        #pragma unroll
        for (int kt2 = 0; kt2 < 2; ++kt2) {
            short8 pa[4];
            #pragma unroll
            for (int mt = 0; mt < 4; ++mt) {
                int row = mt * 16 + lr;
                pa[mt] = *(const short8*)(
                    wb + ((row * 64 + kt2 * 32 + g * 8) ^ ((row & 7) << 3)));
            }
            #pragma unroll
            for (int mt = 0; mt < 4; ++mt)
                #pragma unroll
                for (int dt = 0; dt < 2; ++dt)
                    o[mt][dt] = __builtin_amdgcn_mfma_f32_16x16x32_bf16(
                        pa[mt], vf[kt2 * 2 + dt], o[mt][dt], 0, 0, 0);
        }
        #pragma unroll
        for (int mt = 0; mt < 4; ++mt) {
            short8 p;
            #pragma unroll
            for (int dt = 0; dt < 2; ++dt)
                #pragma unroll
                for (int r = 0; r < 4; ++r)
                    p[dt * 4 + r] = (short)f2bf(o[mt][dt][r]);
            ob16[hi2][mt] = p;
        }
    }
    __syncthreads();   // everyone done with xbf (x data); becomes attn-out

    // ---- attn-out -> xbf region (layout [n][h*32+d], XOR (n&7)<<3) ----
    #pragma unroll
    for (int hi2 = 0; hi2 < 2; ++hi2) {
        int h = wv + hi2 * 4;
        #pragma unroll
        for (int mt = 0; mt < 4; ++mt)
            #pragma unroll
            for (int dt = 0; dt < 2; ++dt) {
                int c = h * 32 + dt * 16 + lr;
                #pragma unroll
                for (int r = 0; r < 4; ++r) {
                    int n = mt * 16 + g * 4 + r;
                    xbf[(n * 256 + c) ^ ((n & 7) << 3)] =
                        (unsigned short)ob16[hi2][mt][dt * 4 + r];
                }
            }
    }
    __syncthreads();

    // ---- out-proj: (64x256) @ (256x256) + bias ----
    f32x4 acc2[4][4];
    #pragma unroll
    for (int i = 0; i < 4; ++i)
        #pragma unroll
        for (int j = 0; j < 4; ++j)
            acc2[i][j] = (f32x4){0.f, 0.f, 0.f, 0.f};
    const int c0 = wv * 64;
    for (int kt = 0; kt < 8; ++kt) {
        short8 af2[4];
        #pragma unroll
        for (int mt = 0; mt < 4; ++mt) {
            int row = mt * 16 + lr;
            af2[mt] = *(const short8*)(
                xbf + ((row * 256 + kt * 32 + g * 8) ^ ((row & 7) << 3)));
        }
        #pragma unroll
        for (int ct = 0; ct < 4; ++ct) {
            short8 bf2 = *(const short8*)(
                wprojT + (size_t)(c0 + ct * 16 + lr) * 256 + kt * 32 + g * 8);
            #pragma unroll
            for (int mt = 0; mt < 4; ++mt)
                acc2[mt][ct] = __builtin_amdgcn_mfma_f32_16x16x32_bf16(
                    af2[mt], bf2, acc2[mt][ct], 0, 0, 0);
        }
    }
    float* ob = out + (size_t)b * NTOK * CDIM;
    #pragma unroll
    for (int ct = 0; ct < 4; ++ct) {
        int c = c0 + ct * 16 + lr;
        float bias = b_proj[c];
        #pragma unroll
        for (int mt = 0; mt < 4; ++mt)
            #pragma unroll
            for (int r = 0; r < 4; ++r) {
                int n = mt * 16 + g * 4 + r;
                ob[n * 256 + c] = acc2[mt][ct][r] + bias;
            }
    }
}

extern "C" void kernel_launch(void* const* d_in, const int* in_sizes, int n_in,
                              void* d_out, int out_size, void* d_ws, size_t ws_size,
                              hipStream_t stream) {
    const float* x      = (const float*)d_in[0];
    const float* mask   = (const float*)d_in[1];
    const float* w_qkv  = (const float*)d_in[2];
    const float* b_qkv  = (const float*)d_in[3];
    const float* w_proj = (const float*)d_in[4];
    const float* b_proj = (const float*)d_in[5];
    float* out = (float*)d_out;

    unsigned short* wqkvT  = (unsigned short*)d_ws;       // 768*256
    unsigned short* wprojT = wqkvT + 768 * 256;           // 256*256

    prep_weights<<<256, 256, 0, stream>>>(w_qkv, w_proj, wqkvT, wprojT);
    swin_fused<<<1024, 256, 0, stream>>>(x, mask, wqkvT, b_qkv,
                                         wprojT, b_proj, out);
}